// Round 18
// baseline (472.177 us; speedup 1.0000x reference)
//
#include <hip/hip_runtime.h>
#include <stdint.h>

typedef __bf16 bf16_t;
typedef __attribute__((ext_vector_type(8))) __bf16 bf16x8;
typedef __attribute__((ext_vector_type(4))) __bf16 bf16x4;
typedef __attribute__((ext_vector_type(4))) float f32x4;

#define NB_ 32
#define NT_ 3136
#define DIN_ 192
#define DOUT_ 384
#define NH_ 6
#define HD_ 64
#define NW_ 49
#define WSZ_ 16
#define TP_ 784
#define MLP_ 1536

__device__ __forceinline__ f32x4 mfma16(bf16x8 a, bf16x8 b, f32x4 c) {
  return __builtin_amdgcn_mfma_f32_16x16x32_bf16(a, b, c, 0, 0, 0);
}

__device__ __forceinline__ void gload_lds16(const bf16_t* g, bf16_t* l) {
  __builtin_amdgcn_global_load_lds(
      (const __attribute__((address_space(1))) void*)((const void*)g),
      (__attribute__((address_space(3))) void*)l, 16, 0, 0);
}

__device__ __forceinline__ float gelu_tanh(float v) {
  const float t2 = 1.5957691216f * (v + 0.044715f * v * v * v);
  return v * (1.f - 1.f / (1.f + __expf(t2)));
}

// ---------------- one-shot f32 -> bf16 weight cache ----------------
__global__ void cvt_kernel(const float* __restrict__ s0, const float* __restrict__ s1,
                           const float* __restrict__ s2, const float* __restrict__ s3,
                           const float* __restrict__ s4, bf16_t* __restrict__ d0,
                           bf16_t* __restrict__ d1, bf16_t* __restrict__ d2,
                           bf16_t* __restrict__ d3, bf16_t* __restrict__ d4) {
  const int b = blockIdx.x;
  const float* s; bf16_t* d; long off;
  if (b < 108)      { s = s0; d = d0; off = (long)b * 2048; }
  else if (b < 144) { s = s1; d = d1; off = (long)(b - 108) * 2048; }
  else if (b < 216) { s = s2; d = d2; off = (long)(b - 144) * 2048; }
  else if (b < 504) { s = s3; d = d3; off = (long)(b - 216) * 2048; }
  else              { s = s4; d = d4; off = (long)(b - 504) * 2048; }
  off += (long)threadIdx.x * 8;
  const float4 a = *(const float4*)(s + off);
  const float4 c = *(const float4*)(s + off + 4);
  bf16x8 o;
  o[0] = (bf16_t)a.x; o[1] = (bf16_t)a.y; o[2] = (bf16_t)a.z; o[3] = (bf16_t)a.w;
  o[4] = (bf16_t)c.x; o[5] = (bf16_t)c.y; o[6] = (bf16_t)c.z; o[7] = (bf16_t)c.w;
  *(bf16x8*)(d + off) = o;
}

// ---------------- LayerNorm f32 -> bf16 ----------------
template <int D>
__global__ void ln_f32_kernel(const float* __restrict__ in, const float* __restrict__ w,
                              const float* __restrict__ bvec, bf16_t* __restrict__ out) {
  const int row = blockIdx.x * 4 + (threadIdx.x >> 6);
  const int lane = threadIdx.x & 63;
  constexpr int PER = D / 64;
  const float* x = in + (long)row * D;
  float v[PER];
  float s = 0.f;
#pragma unroll
  for (int i = 0; i < PER; i++) { v[i] = x[lane * PER + i]; s += v[i]; }
#pragma unroll
  for (int off = 1; off < 64; off <<= 1) s += __shfl_xor(s, off);
  const float mu = s * (1.f / D);
  float s2 = 0.f;
#pragma unroll
  for (int i = 0; i < PER; i++) { const float d = v[i] - mu; s2 += d * d; }
#pragma unroll
  for (int off = 1; off < 64; off <<= 1) s2 += __shfl_xor(s2, off);
  const float rstd = rsqrtf(s2 * (1.f / D) + 1e-5f);
  bf16_t* o = out + (long)row * D;
#pragma unroll
  for (int i = 0; i < PER; i++) {
    const int c = lane * PER + i;
    o[c] = (bf16_t)((v[i] - mu) * rstd * w[c] + bvec[c]);
  }
}

// ---------------- LayerNorm bf16 -> bf16 ----------------
template <int D>
__global__ void ln_bf16_kernel(const bf16_t* __restrict__ in, const float* __restrict__ w,
                               const float* __restrict__ bvec, bf16_t* __restrict__ out) {
  const int row = blockIdx.x * 4 + (threadIdx.x >> 6);
  const int lane = threadIdx.x & 63;
  constexpr int PER = D / 64;
  const bf16_t* x = in + (long)row * D;
  float v[PER];
  float s = 0.f;
#pragma unroll
  for (int i = 0; i < PER; i++) { v[i] = (float)x[lane * PER + i]; s += v[i]; }
#pragma unroll
  for (int off = 1; off < 64; off <<= 1) s += __shfl_xor(s, off);
  const float mu = s * (1.f / D);
  float s2 = 0.f;
#pragma unroll
  for (int i = 0; i < PER; i++) { const float d = v[i] - mu; s2 += d * d; }
#pragma unroll
  for (int off = 1; off < 64; off <<= 1) s2 += __shfl_xor(s2, off);
  const float rstd = rsqrtf(s2 * (1.f / D) + 1e-5f);
  bf16_t* o = out + (long)row * D;
#pragma unroll
  for (int i = 0; i < PER; i++) {
    const int c = lane * PER + i;
    o[c] = (bf16_t)((v[i] - mu) * rstd * w[c] + bvec[c]);
  }
}

// ===== 8-wave GEMM: 256x128 tile (res / fc1), staged coalesced epilogue =====
template <int ACT, int POOL>
__global__ __launch_bounds__(512, 4) void gemm8(
    const bf16_t* __restrict__ A, const bf16_t* __restrict__ W,
    const float* __restrict__ bias, bf16_t* __restrict__ C,
    int M, int N, int K) {
  __shared__ __align__(16) char AsB[256 * 128];
  __shared__ __align__(16) char WsB[128 * 128];

  const int nwg = gridDim.x;
  const int q = nwg >> 3, rm = nwg & 7;
  const int xcd = blockIdx.x & 7, idx = blockIdx.x >> 3;
  const int wg = (xcd < rm ? xcd * (q + 1) : rm * (q + 1) + (xcd - rm) * q) + idx;

  const int nbn = N >> 7;
  const int bmi = wg / nbn;
  const int bni = wg - bmi * nbn;
  const int m0 = bmi << 8, n0 = bni << 7;
  const int tid = threadIdx.x;
  const int lane = tid & 63;
  const int wid = tid >> 6;
  const int wr = (wid >> 1) * 64, wc = (wid & 1) * 64;
  const int l15 = lane & 15;
  const int lkb = (lane >> 4) << 4;
  const int srow = tid >> 3;
  const int scolsw = ((tid & 7) << 3) ^ ((srow & 7) << 3);
  const int swzr = (l15 & 7) << 4;

  f32x4 acc[4][4];
  const f32x4 zero = {0.f, 0.f, 0.f, 0.f};
#pragma unroll
  for (int i = 0; i < 4; i++)
#pragma unroll
    for (int j = 0; j < 4; j++) acc[i][j] = zero;

  long arow[4];
#pragma unroll
  for (int p = 0; p < 4; p++) {
    const int m = m0 + p * 64 + srow;
    if constexpr (POOL) {
      const int b = m / NT_;
      const int mm = m - b * NT_;
      arow[p] = (long)b * NT_ + (mm & 3) * TP_ + (mm >> 2);
    } else {
      arow[p] = m;
    }
  }
  long wrow[2];
#pragma unroll
  for (int p = 0; p < 2; p++) wrow[p] = (long)(n0 + p * 64 + srow);

  for (int k0 = 0; k0 < K; k0 += 64) {
    __syncthreads();
#pragma unroll
    for (int p = 0; p < 4; p++)
      gload_lds16(A + arow[p] * K + k0 + scolsw, (bf16_t*)(AsB + p * 8192 + tid * 16));
#pragma unroll
    for (int p = 0; p < 2; p++)
      gload_lds16(W + wrow[p] * K + k0 + scolsw, (bf16_t*)(WsB + p * 8192 + tid * 16));
    __syncthreads();
#pragma unroll
    for (int kk = 0; kk < 2; kk++) {
      bf16x8 af[4], wf[4];
#pragma unroll
      for (int i = 0; i < 4; i++)
        af[i] = *(const bf16x8*)(AsB + (wr + i * 16 + l15) * 128 + ((kk * 64 + lkb) ^ swzr));
#pragma unroll
      for (int j = 0; j < 4; j++)
        wf[j] = *(const bf16x8*)(WsB + (wc + j * 16 + l15) * 128 + ((kk * 64 + lkb) ^ swzr));
#pragma unroll
      for (int i = 0; i < 4; i++)
#pragma unroll
        for (int j = 0; j < 4; j++) {
          if constexpr (POOL) acc[i][j] = mfma16(af[i], wf[j], acc[i][j]);
          else                acc[i][j] = mfma16(wf[j], af[i], acc[i][j]);
        }
    }
  }

  const int rg = (lane >> 4) * 4;
  if constexpr (POOL) {
#pragma unroll
    for (int j = 0; j < 4; j++) {
      const int gn = n0 + wc + j * 16 + l15;
      const float bv = bias[gn];
#pragma unroll
      for (int i = 0; i < 4; i++) {
        const float v = fmaxf(fmaxf(acc[i][j][0], acc[i][j][1]),
                              fmaxf(acc[i][j][2], acc[i][j][3])) + bv;
        const long pm = (long)((m0 + wr + i * 16 + rg) >> 2);
        C[pm * N + gn] = (bf16_t)v;
      }
    }
  } else {
    __syncthreads();
    char* scr = AsB + wid * 4096;
#pragma unroll
    for (int i = 0; i < 4; i++) {
#pragma unroll
      for (int j = 0; j < 4; j++)
        *(f32x4*)(scr + l15 * 256 + ((((j * 16 + rg) << 2)) ^ ((l15 & 7) << 4))) = acc[i][j];
#pragma unroll
      for (int k = 0; k < 4; k++) {
        const int rl = k * 4 + (lane >> 4);
        const int cb = (lane & 15) << 4;
        const f32x4 v = *(const f32x4*)(scr + rl * 256 + (cb ^ ((rl & 7) << 4)));
        const long gm = m0 + wr + i * 16 + rl;
        const int gn = n0 + wc + ((lane & 15) << 2);
        const float4 bv = *(const float4*)(bias + gn);
        float vv[4] = {v[0] + bv.x, v[1] + bv.y, v[2] + bv.z, v[3] + bv.w};
        if constexpr (ACT == 1) {
#pragma unroll
          for (int r = 0; r < 4; r++) vv[r] = gelu_tanh(vv[r]);
        }
        bf16x4 o;
#pragma unroll
        for (int r = 0; r < 4; r++) o[r] = (bf16_t)vv[r];
        *(bf16x4*)(C + gm * N + gn) = o;
      }
    }
  }
}

// ===== 4-wave GEMM (dbuf, BM=64) — proj / fc2, staged coalesced epilogue =====
template <int HASRES, int OF32, int RF32>
__global__ __launch_bounds__(256) void gemm_t(
    const bf16_t* __restrict__ A, const bf16_t* __restrict__ W,
    const float* __restrict__ bias, const void* __restrict__ resv,
    void* __restrict__ Cv, int M, int N, int K) {
  constexpr int BM = 64;
  constexpr int PA = BM / 32;
  constexpr int ABYTES = BM * 128;
  constexpr int BUFSZ = ABYTES + 128 * 128;
  __shared__ __align__(16) char LDSB[2 * BUFSZ];

  const int nwg = gridDim.x;
  const int q = nwg >> 3, rm = nwg & 7;
  const int xcd = blockIdx.x & 7, idx = blockIdx.x >> 3;
  const int wg = (xcd < rm ? xcd * (q + 1) : rm * (q + 1) + (xcd - rm) * q) + idx;

  const int nbn = N >> 7;
  const int bmi = wg / nbn;
  const int bni = wg - bmi * nbn;
  const int m0 = bmi * BM, n0 = bni << 7;
  const int tid = threadIdx.x;
  const int lane = tid & 63;
  const int wid = tid >> 6;
  const int wr = (wid >> 1) * 32, wc = (wid & 1) * 64;
  const int l15 = lane & 15;
  const int lkb = (lane >> 4) << 4;
  const int srow = tid >> 3;
  const int scolsw = ((tid & 7) << 3) ^ ((srow & 7) << 3);
  const int swzr = (l15 & 7) << 4;

  f32x4 acc[PA][4];
  const f32x4 zero = {0.f, 0.f, 0.f, 0.f};
#pragma unroll
  for (int i = 0; i < PA; i++)
#pragma unroll
    for (int j = 0; j < 4; j++) acc[i][j] = zero;

  long arow[PA];
#pragma unroll
  for (int p = 0; p < PA; p++) arow[p] = m0 + srow + p * 32;
  long wrow[4];
#pragma unroll
  for (int p = 0; p < 4; p++) wrow[p] = (long)(n0 + srow + p * 32);

  auto stage = [&](int buf, int k0) {
    char* base = LDSB + buf * BUFSZ;
#pragma unroll
    for (int p = 0; p < PA; p++)
      gload_lds16(A + arow[p] * K + k0 + scolsw, (bf16_t*)(base + p * 4096 + tid * 16));
#pragma unroll
    for (int p = 0; p < 4; p++)
      gload_lds16(W + wrow[p] * K + k0 + scolsw,
                  (bf16_t*)(base + ABYTES + p * 4096 + tid * 16));
  };

  const int nt = K >> 6;
  stage(0, 0);
  int cur = 0;
  for (int t = 0; t < nt; t++) {
    __syncthreads();
    if (t + 1 < nt) stage(cur ^ 1, (t + 1) << 6);
    const char* base = LDSB + cur * BUFSZ;
#pragma unroll
    for (int kk = 0; kk < 2; kk++) {
      bf16x8 af[PA], wf[4];
#pragma unroll
      for (int i = 0; i < PA; i++)
        af[i] = *(const bf16x8*)(base + (wr + i * 16 + l15) * 128 + ((kk * 64 + lkb) ^ swzr));
#pragma unroll
      for (int j = 0; j < 4; j++)
        wf[j] = *(const bf16x8*)(base + ABYTES + (wc + j * 16 + l15) * 128 +
                                 ((kk * 64 + lkb) ^ swzr));
#pragma unroll
      for (int i = 0; i < PA; i++)
#pragma unroll
        for (int j = 0; j < 4; j++) acc[i][j] = mfma16(wf[j], af[i], acc[i][j]);
    }
    cur ^= 1;
  }

  __syncthreads();
  char* scr = LDSB + wid * 8192;
  const int rg = (lane >> 4) * 4;
#pragma unroll
  for (int i = 0; i < PA; i++) {
    const int ml = i * 16 + l15;
#pragma unroll
    for (int j = 0; j < 4; j++)
      *(f32x4*)(scr + ml * 256 + ((((j * 16 + rg) << 2)) ^ ((ml & 7) << 4))) = acc[i][j];
  }
#pragma unroll
  for (int k = 0; k < 8; k++) {
    const int rl = k * 4 + (lane >> 4);
    const int cb = (lane & 15) << 4;
    const f32x4 v = *(const f32x4*)(scr + rl * 256 + (cb ^ ((rl & 7) << 4)));
    const long gm = m0 + wr + rl;
    const int gn = n0 + wc + ((lane & 15) << 2);
    const float4 bv = *(const float4*)(bias + gn);
    float vv[4] = {v[0] + bv.x, v[1] + bv.y, v[2] + bv.z, v[3] + bv.w};
    if constexpr (HASRES) {
      if constexpr (RF32) {
        const float4 rv = *(const float4*)((const float*)resv + gm * N + gn);
        vv[0] += rv.x; vv[1] += rv.y; vv[2] += rv.z; vv[3] += rv.w;
      } else {
        const bf16x4 rv = *(const bf16x4*)((const bf16_t*)resv + gm * N + gn);
#pragma unroll
        for (int r = 0; r < 4; r++) vv[r] += (float)rv[r];
      }
    }
    if constexpr (OF32) {
      float4 o = {vv[0], vv[1], vv[2], vv[3]};
      *(float4*)((float*)Cv + gm * N + gn) = o;
    } else {
      bf16x4 o;
#pragma unroll
      for (int r = 0; r < 4; r++) o[r] = (bf16_t)vv[r];
      *(bf16x4*)((bf16_t*)Cv + gm * N + gn) = o;
    }
  }
}

// ===== FUSED qkv + attention v3: one block = (batch-PAIR, window), 6 waves =====
// Each wave computes its head for TWO batches with ONE W-fragment load
// (acc0/acc1 share wf) -> W-gather count per unit work halves; per-j MFMA
// cluster doubles to 48, covering the L2 latency. Phases (pool/bounce/softmax/
// PV/staged stores) = verified r17 code run per batch on per-wave buffers.
__global__ __launch_bounds__(384, 2) void qkv_attn_kernel(
    const bf16_t* __restrict__ x, const bf16_t* __restrict__ Wqkv,
    const float* __restrict__ bq, float* __restrict__ prob,
    bf16_t* __restrict__ obuf) {
  __shared__ __align__(16) char As[2 * 24576];    // two x-tiles, swizzled
  __shared__ __align__(16) char Qs[6][4096];      // per-wave Qp/P/O, 2KB per batch
  __shared__ __align__(16) char Kb[6][4096];      // per-wave K/V bounce (time-shared)
  const int bp = blockIdx.x / NW_;
  const int w = blockIdx.x - bp * NW_;
  const int b0 = bp * 2;
  const int tid = threadIdx.x;
  const int lane = tid & 63;
  const int h = tid >> 6;                         // wave = head
  const int l15 = lane & 15;
  const int lk8 = (lane >> 4) * 8;
  const int lkb = (lane >> 4) << 4;
  const int rg = (lane >> 4) * 4;
  const f32x4 zero = {0.f, 0.f, 0.f, 0.f};
  char* Qw = Qs[h];
  char* Bw = Kb[h];

  // ---- stage both x-tiles (rows inner=0..63, t = inner*49 + w), swizzled src ----
#pragma unroll
  for (int u = 0; u < 8; u++) {
    const int bi = u >> 2;
    const int row = (u & 3) * 16 + tid / 24;
    const int cb = ((tid % 24) * 16) ^ ((row & 7) << 4);
    gload_lds16(x + ((long)(b0 + bi) * NT_ + (long)row * NW_ + w) * DIN_ + cb / 2,
                (bf16_t*)(As + bi * 24576 + (u & 3) * 6144 + tid * 16));
  }
  __syncthreads();

  auto afrag = [&](int bi, int mr, int ks) {
    return *(const bf16x8*)(As + bi * 24576 + mr * 384 +
                            ((ks * 64 + lkb) ^ ((mr & 7) << 4)));
  };

  f32x4 acc0[4][4], acc1[4][4];
  auto gemm2 = [&](int which) {
#pragma unroll
    for (int i = 0; i < 4; i++)
#pragma unroll
      for (int j = 0; j < 4; j++) { acc0[i][j] = zero; acc1[i][j] = zero; }
#pragma unroll
    for (int j = 0; j < 4; j++) {
      const bf16_t* wrow = Wqkv + (long)(which * DOUT_ + h * HD_ + j * 16 + l15) * DIN_;
      bf16x8 wf[6];
#pragma unroll
      for (int ks = 0; ks < 6; ks++) wf[ks] = *(const bf16x8*)(wrow + ks * 32 + lk8);
#pragma unroll
      for (int ks = 0; ks < 6; ks++) {
#pragma unroll
        for (int i = 0; i < 4; i++) {
          const int mr = i * 16 + l15;
          acc0[i][j] = mfma16(afrag(0, mr, ks), wf[ks], acc0[i][j]);
          acc1[i][j] = mfma16(afrag(1, mr, ks), wf[ks], acc1[i][j]);
        }
      }
    }
  };

  // ======== q part (both batches share wf) ========
  gemm2(0);
  auto qpool = [&](f32x4 (&A)[4][4], int bi) {
#pragma unroll
    for (int j = 0; j < 4; j++) {
      const float bb = bq[h * HD_ + j * 16 + l15];
#pragma unroll
      for (int r = 0; r < 4; r++) {
        const float v = (fmaxf(fmaxf(A[0][j][r], A[1][j][r]),
                               fmaxf(A[2][j][r], A[3][j][r])) + bb) * 0.125f;
        const int row = rg + r;
        *(bf16_t*)(Qw + bi * 2048 + row * 128 +
                   (((j * 16 + l15) * 2) ^ ((row & 7) << 4))) = (bf16_t)v;
      }
    }
  };
  qpool(acc0, 0);
  qpool(acc1, 1);
  bf16x8 aq0[2], aq1[2];
#pragma unroll
  for (int kc = 0; kc < 2; kc++) {
    aq0[kc] = *(const bf16x8*)(Qw + l15 * 128 + ((kc * 64 + lkb) ^ ((l15 & 7) << 4)));
    aq1[kc] = *(const bf16x8*)(Qw + 2048 + l15 * 128 + ((kc * 64 + lkb) ^ ((l15 & 7) << 4)));
  }

  // ======== k part ========
  gemm2(1);
  auto addbias = [&](f32x4 (&A)[4][4], int base) {
#pragma unroll
    for (int j = 0; j < 4; j++) {
      const float bb = bq[base + h * HD_ + j * 16 + l15];
#pragma unroll
      for (int i = 0; i < 4; i++)
#pragma unroll
        for (int r = 0; r < 4; r++) A[i][j][r] += bb;
    }
  };
  addbias(acc0, DOUT_);
  addbias(acc1, DOUT_);
  f32x4 s40[4], s41[4];
  auto sgemm = [&](f32x4 (&A)[4][4], bf16x8 (&aq)[2], f32x4 (&s4)[4]) {
#pragma unroll
    for (int nc = 0; nc < 4; nc++) s4[nc] = zero;
#pragma unroll
    for (int t = 0; t < 2; t++) {
#pragma unroll
      for (int i2 = 0; i2 < 2; i2++) {
        const int i = t * 2 + i2;
#pragma unroll
        for (int j = 0; j < 4; j++)
#pragma unroll
          for (int r = 0; r < 4; r++) {
            const int tokh = i2 * 16 + rg + r;
            *(bf16_t*)(Bw + tokh * 128 + (((j * 16 + l15) * 2) ^ ((tokh & 7) << 4))) =
                (bf16_t)A[i][j][r];
          }
      }
#pragma unroll
      for (int nch = 0; nch < 2; nch++) {
        const int nc = t * 2 + nch;
        const int tokh = nch * 16 + l15;
#pragma unroll
        for (int kc = 0; kc < 2; kc++) {
          const bf16x8 bk = *(const bf16x8*)(Bw + tokh * 128 +
                                             ((kc * 64 + lkb) ^ ((tokh & 7) << 4)));
          s4[nc] = mfma16(aq[kc], bk, s4[nc]);
        }
      }
    }
  };
  sgemm(acc0, aq0, s40);
  sgemm(acc1, aq1, s41);

  // ======== softmax + prob write + P stage (per batch) ========
  auto smax = [&](f32x4 (&s4)[4], int bglob, int bi) {
#pragma unroll
    for (int r = 0; r < 4; r++) {
      float mx = fmaxf(fmaxf(s4[0][r], s4[1][r]), fmaxf(s4[2][r], s4[3][r]));
#pragma unroll
      for (int off = 1; off < 16; off <<= 1) mx = fmaxf(mx, __shfl_xor(mx, off));
      float sm = 0.f;
#pragma unroll
      for (int nc = 0; nc < 4; nc++) {
        const float p = __expf(s4[nc][r] - mx);
        s4[nc][r] = p;
        sm += p;
      }
#pragma unroll
      for (int off = 1; off < 16; off <<= 1) sm += __shfl_xor(sm, off);
      const float inv = 1.f / sm;
#pragma unroll
      for (int nc = 0; nc < 4; nc++) s4[nc][r] *= inv;
    }
    float* aout = prob + (long)((bglob * NH_ + h) * NW_ + w) * (WSZ_ * 64);
#pragma unroll
    for (int nc = 0; nc < 4; nc++) {
#pragma unroll
      for (int r = 0; r < 4; r++) {
        const int row = rg + r, col = nc * 16 + l15;
        aout[row * 64 + col] = s4[nc][r];
        *(bf16_t*)(Qw + bi * 2048 + row * 128 + ((col * 2) ^ ((row & 7) << 4))) =
            (bf16_t)s4[nc][r];
      }
    }
  };
  smax(s40, b0, 0);
  smax(s41, b0 + 1, 1);
  bf16x8 ap0[2], ap1[2];
#pragma unroll
  for (int kc = 0; kc < 2; kc++) {
    ap0[kc] = *(const bf16x8*)(Qw + l15 * 128 + ((kc * 64 + lkb) ^ ((l15 & 7) << 4)));
    ap1[kc] = *(const bf16x8*)(Qw + 2048 + l15 * 128 + ((kc * 64 + lkb) ^ ((l15 & 7) << 4)));
  }

  // ======== v part ========
  gemm2(2);
  addbias(acc0, 2 * DOUT_);
  addbias(acc1, 2 * DOUT_);
  auto pv = [&](f32x4 (&A)[4][4], bf16x8 (&ap)[2], int bglob, int bi) {
    f32x4 o4[4];
#pragma unroll
    for (int nc = 0; nc < 4; nc++) o4[nc] = zero;
#pragma unroll
    for (int t = 0; t < 2; t++) {
#pragma unroll
      for (int i2 = 0; i2 < 2; i2++) {
        const int i = t * 2 + i2;
#pragma unroll
        for (int j = 0; j < 4; j++)
#pragma unroll
          for (int r = 0; r < 4; r++) {
            const int tokh = i2 * 16 + rg + r;
            *(bf16_t*)(Bw + tokh * 128 + (((j * 16 + l15) * 2) ^ ((tokh & 7) << 4))) =
                (bf16_t)A[i][j][r];
          }
      }
#pragma unroll
      for (int nc = 0; nc < 4; nc++) {
        bf16x8 bv;
#pragma unroll
        for (int e = 0; e < 8; e++) {
          const int tokh = lk8 + e;
          bv[e] = *(const bf16_t*)(Bw + tokh * 128 +
                                   (((nc * 16 + l15) * 2) ^ ((tokh & 7) << 4)));
        }
        o4[nc] = mfma16(ap[t], bv, o4[nc]);
      }
    }
    // staged obuf write through Qw (P dead)
#pragma unroll
    for (int nc = 0; nc < 4; nc++) {
#pragma unroll
      for (int r = 0; r < 4; r++) {
        const int row = rg + r;
        *(bf16_t*)(Qw + bi * 2048 + row * 128 +
                   (((nc * 16 + l15) * 2) ^ ((row & 7) << 4))) = (bf16_t)o4[nc][r];
      }
    }
    bf16_t* ob = obuf + (long)bglob * TP_ * DOUT_ + h * HD_;
#pragma unroll
    for (int p = 0; p < 2; p++) {
      const int row = lane >> 2;
      const int cb = p * 64 + (lane & 3) * 16;
      const bf16x8 t = *(const bf16x8*)(Qw + bi * 2048 + row * 128 + (cb ^ ((row & 7) << 4)));
      *(bf16x8*)(ob + (long)(row * NW_ + w) * DOUT_ + cb / 2) = t;
    }
  };
  pv(acc0, ap0, b0, 0);
  pv(acc1, ap1, b0 + 1, 1);
}

extern "C" void kernel_launch(void* const* d_in, const int* in_sizes, int n_in,
                              void* d_out, int out_size, void* d_ws, size_t ws_size,
                              hipStream_t stream) {
  const float* emb   = (const float*)d_in[0];
  const float* n1w   = (const float*)d_in[1];
  const float* n1b   = (const float*)d_in[2];
  const float* wqkv  = (const float*)d_in[3];
  const float* bqkv  = (const float*)d_in[4];
  const float* wproj = (const float*)d_in[5];
  const float* bproj = (const float*)d_in[6];
  const float* wres  = (const float*)d_in[7];
  const float* bres  = (const float*)d_in[8];
  const float* n2w   = (const float*)d_in[9];
  const float* n2b   = (const float*)d_in[10];
  const float* wfc1  = (const float*)d_in[11];
  const float* bfc1  = (const float*)d_in[12];
  const float* wfc2  = (const float*)d_in[13];
  const float* bfc2  = (const float*)d_in[14];
  float* out = (float*)d_out;

  const int BT = NB_ * NT_;    // 100352
  const int BTP = NB_ * TP_;   // 25088

  char* wsb = (char*)d_ws;
  bf16_t* x    = (bf16_t*)(wsb);
  bf16_t* h1   = (bf16_t*)(wsb);
  bf16_t* obuf = (bf16_t*)(wsb + 57802752L);
  bf16_t* resp = (bf16_t*)(wsb + 77070336L);
  bf16_t* h0   = resp;
  bf16_t* emb1 = (bf16_t*)(wsb + 96337920L);
  bf16_t* wbqkv = (bf16_t*)(wsb + 115605504L);
  bf16_t* wbres = wbqkv + 221184L;
  bf16_t* wbproj = wbres + 73728L;
  bf16_t* wbfc1 = wbproj + 147456L;
  bf16_t* wbfc2 = wbfc1 + 589824L;
  float*  prob = out + 9633792L;   // attn-probs half of d_out

  // 0. weight cache f32 -> bf16
  cvt_kernel<<<792, 256, 0, stream>>>(wqkv, wres, wproj, wfc1, wfc2,
                                      wbqkv, wbres, wbproj, wbfc1, wbfc2);
  // 1. LN1: emb f32 -> x bf16 (ws)
  ln_f32_kernel<DIN_><<<BT / 4, 256, 0, stream>>>(emb, n1w, n1b, x);
  // 2. res projection + fused q-stride max-pool -> resp bf16
  gemm8<0, 1><<<(BT / 256) * (DOUT_ / 128), 512, 0, stream>>>(
      x, wbres, bres, resp, BT, DOUT_, DIN_);
  // 3. FUSED qkv + attention (batch-paired) -> prob (d_out) + obuf
  qkv_attn_kernel<<<(NB_ / 2) * NW_, 384, 0, stream>>>(x, wbqkv, bqkv, prob, obuf);
  // 4. attn proj + pooled residual -> emb1 bf16
  gemm_t<1, 0, 0><<<(BTP / 64) * (DOUT_ / 128), 256, 0, stream>>>(
      obuf, wbproj, bproj, resp, emb1, BTP, DOUT_, DOUT_);
  // 5. LN2: emb1 bf16 -> h0 bf16
  ln_bf16_kernel<DOUT_><<<BTP / 4, 256, 0, stream>>>(emb1, n2w, n2b, h0);
  // 6. fc1 + GELU -> h1 bf16
  gemm8<1, 0><<<(BTP / 256) * (MLP_ / 128), 512, 0, stream>>>(
      h0, wbfc1, bfc1, h1, BTP, MLP_, DOUT_);
  // 7. fc2 + emb1 residual -> d_out emb half f32
  gemm_t<1, 1, 0><<<(BTP / 64) * (DOUT_ / 128), 256, 0, stream>>>(
      h1, wbfc2, bfc2, emb1, out, BTP, DOUT_, MLP_);
}

// Round 20
// 311.870 us; speedup vs baseline: 1.5140x; 1.5140x over previous
//
#include <hip/hip_runtime.h>
#include <stdint.h>

typedef __bf16 bf16_t;
typedef __attribute__((ext_vector_type(8))) __bf16 bf16x8;
typedef __attribute__((ext_vector_type(4))) __bf16 bf16x4;
typedef __attribute__((ext_vector_type(4))) float f32x4;

#define NB_ 32
#define NT_ 3136
#define DIN_ 192
#define DOUT_ 384
#define NH_ 6
#define HD_ 64
#define NW_ 49
#define WSZ_ 16
#define TP_ 784
#define MLP_ 1536

__device__ __forceinline__ f32x4 mfma16(bf16x8 a, bf16x8 b, f32x4 c) {
  return __builtin_amdgcn_mfma_f32_16x16x32_bf16(a, b, c, 0, 0, 0);
}

__device__ __forceinline__ void gload_lds16(const bf16_t* g, bf16_t* l) {
  __builtin_amdgcn_global_load_lds(
      (const __attribute__((address_space(1))) void*)((const void*)g),
      (__attribute__((address_space(3))) void*)l, 16, 0, 0);
}

__device__ __forceinline__ float gelu_tanh(float v) {
  const float t2 = 1.5957691216f * (v + 0.044715f * v * v * v);
  return v * (1.f - 1.f / (1.f + __expf(t2)));
}

// ---------------- one-shot f32 -> bf16 weight cache ----------------
__global__ void cvt_kernel(const float* __restrict__ s0, const float* __restrict__ s1,
                           const float* __restrict__ s2, const float* __restrict__ s3,
                           const float* __restrict__ s4, bf16_t* __restrict__ d0,
                           bf16_t* __restrict__ d1, bf16_t* __restrict__ d2,
                           bf16_t* __restrict__ d3, bf16_t* __restrict__ d4) {
  const int b = blockIdx.x;
  const float* s; bf16_t* d; long off;
  if (b < 108)      { s = s0; d = d0; off = (long)b * 2048; }
  else if (b < 144) { s = s1; d = d1; off = (long)(b - 108) * 2048; }
  else if (b < 216) { s = s2; d = d2; off = (long)(b - 144) * 2048; }
  else if (b < 504) { s = s3; d = d3; off = (long)(b - 216) * 2048; }
  else              { s = s4; d = d4; off = (long)(b - 504) * 2048; }
  off += (long)threadIdx.x * 8;
  const float4 a = *(const float4*)(s + off);
  const float4 c = *(const float4*)(s + off + 4);
  bf16x8 o;
  o[0] = (bf16_t)a.x; o[1] = (bf16_t)a.y; o[2] = (bf16_t)a.z; o[3] = (bf16_t)a.w;
  o[4] = (bf16_t)c.x; o[5] = (bf16_t)c.y; o[6] = (bf16_t)c.z; o[7] = (bf16_t)c.w;
  *(bf16x8*)(d + off) = o;
}

// ---------------- LayerNorm f32 -> bf16 ----------------
template <int D>
__global__ void ln_f32_kernel(const float* __restrict__ in, const float* __restrict__ w,
                              const float* __restrict__ bvec, bf16_t* __restrict__ out) {
  const int row = blockIdx.x * 4 + (threadIdx.x >> 6);
  const int lane = threadIdx.x & 63;
  constexpr int PER = D / 64;
  const float* x = in + (long)row * D;
  float v[PER];
  float s = 0.f;
#pragma unroll
  for (int i = 0; i < PER; i++) { v[i] = x[lane * PER + i]; s += v[i]; }
#pragma unroll
  for (int off = 1; off < 64; off <<= 1) s += __shfl_xor(s, off);
  const float mu = s * (1.f / D);
  float s2 = 0.f;
#pragma unroll
  for (int i = 0; i < PER; i++) { const float d = v[i] - mu; s2 += d * d; }
#pragma unroll
  for (int off = 1; off < 64; off <<= 1) s2 += __shfl_xor(s2, off);
  const float rstd = rsqrtf(s2 * (1.f / D) + 1e-5f);
  bf16_t* o = out + (long)row * D;
#pragma unroll
  for (int i = 0; i < PER; i++) {
    const int c = lane * PER + i;
    o[c] = (bf16_t)((v[i] - mu) * rstd * w[c] + bvec[c]);
  }
}

// ---------------- LayerNorm bf16 -> bf16 ----------------
template <int D>
__global__ void ln_bf16_kernel(const bf16_t* __restrict__ in, const float* __restrict__ w,
                               const float* __restrict__ bvec, bf16_t* __restrict__ out) {
  const int row = blockIdx.x * 4 + (threadIdx.x >> 6);
  const int lane = threadIdx.x & 63;
  constexpr int PER = D / 64;
  const bf16_t* x = in + (long)row * D;
  float v[PER];
  float s = 0.f;
#pragma unroll
  for (int i = 0; i < PER; i++) { v[i] = (float)x[lane * PER + i]; s += v[i]; }
#pragma unroll
  for (int off = 1; off < 64; off <<= 1) s += __shfl_xor(s, off);
  const float mu = s * (1.f / D);
  float s2 = 0.f;
#pragma unroll
  for (int i = 0; i < PER; i++) { const float d = v[i] - mu; s2 += d * d; }
#pragma unroll
  for (int off = 1; off < 64; off <<= 1) s2 += __shfl_xor(s2, off);
  const float rstd = rsqrtf(s2 * (1.f / D) + 1e-5f);
  bf16_t* o = out + (long)row * D;
#pragma unroll
  for (int i = 0; i < PER; i++) {
    const int c = lane * PER + i;
    o[c] = (bf16_t)((v[i] - mu) * rstd * w[c] + bvec[c]);
  }
}

// ===== 8-wave GEMM: 256x128 tile (res / fc1), staged coalesced epilogue =====
template <int ACT, int POOL>
__global__ __launch_bounds__(512, 4) void gemm8(
    const bf16_t* __restrict__ A, const bf16_t* __restrict__ W,
    const float* __restrict__ bias, bf16_t* __restrict__ C,
    int M, int N, int K) {
  __shared__ __align__(16) char AsB[256 * 128];
  __shared__ __align__(16) char WsB[128 * 128];

  const int nwg = gridDim.x;
  const int q = nwg >> 3, rm = nwg & 7;
  const int xcd = blockIdx.x & 7, idx = blockIdx.x >> 3;
  const int wg = (xcd < rm ? xcd * (q + 1) : rm * (q + 1) + (xcd - rm) * q) + idx;

  const int nbn = N >> 7;
  const int bmi = wg / nbn;
  const int bni = wg - bmi * nbn;
  const int m0 = bmi << 8, n0 = bni << 7;
  const int tid = threadIdx.x;
  const int lane = tid & 63;
  const int wid = tid >> 6;
  const int wr = (wid >> 1) * 64, wc = (wid & 1) * 64;
  const int l15 = lane & 15;
  const int lkb = (lane >> 4) << 4;
  const int srow = tid >> 3;
  const int scolsw = ((tid & 7) << 3) ^ ((srow & 7) << 3);
  const int swzr = (l15 & 7) << 4;

  f32x4 acc[4][4];
  const f32x4 zero = {0.f, 0.f, 0.f, 0.f};
#pragma unroll
  for (int i = 0; i < 4; i++)
#pragma unroll
    for (int j = 0; j < 4; j++) acc[i][j] = zero;

  long arow[4];
#pragma unroll
  for (int p = 0; p < 4; p++) {
    const int m = m0 + p * 64 + srow;
    if constexpr (POOL) {
      const int b = m / NT_;
      const int mm = m - b * NT_;
      arow[p] = (long)b * NT_ + (mm & 3) * TP_ + (mm >> 2);
    } else {
      arow[p] = m;
    }
  }
  long wrow[2];
#pragma unroll
  for (int p = 0; p < 2; p++) wrow[p] = (long)(n0 + p * 64 + srow);

  for (int k0 = 0; k0 < K; k0 += 64) {
    __syncthreads();
#pragma unroll
    for (int p = 0; p < 4; p++)
      gload_lds16(A + arow[p] * K + k0 + scolsw, (bf16_t*)(AsB + p * 8192 + tid * 16));
#pragma unroll
    for (int p = 0; p < 2; p++)
      gload_lds16(W + wrow[p] * K + k0 + scolsw, (bf16_t*)(WsB + p * 8192 + tid * 16));
    __syncthreads();
#pragma unroll
    for (int kk = 0; kk < 2; kk++) {
      bf16x8 af[4], wf[4];
#pragma unroll
      for (int i = 0; i < 4; i++)
        af[i] = *(const bf16x8*)(AsB + (wr + i * 16 + l15) * 128 + ((kk * 64 + lkb) ^ swzr));
#pragma unroll
      for (int j = 0; j < 4; j++)
        wf[j] = *(const bf16x8*)(WsB + (wc + j * 16 + l15) * 128 + ((kk * 64 + lkb) ^ swzr));
#pragma unroll
      for (int i = 0; i < 4; i++)
#pragma unroll
        for (int j = 0; j < 4; j++) {
          if constexpr (POOL) acc[i][j] = mfma16(af[i], wf[j], acc[i][j]);
          else                acc[i][j] = mfma16(wf[j], af[i], acc[i][j]);
        }
    }
  }

  const int rg = (lane >> 4) * 4;
  if constexpr (POOL) {
#pragma unroll
    for (int j = 0; j < 4; j++) {
      const int gn = n0 + wc + j * 16 + l15;
      const float bv = bias[gn];
#pragma unroll
      for (int i = 0; i < 4; i++) {
        const float v = fmaxf(fmaxf(acc[i][j][0], acc[i][j][1]),
                              fmaxf(acc[i][j][2], acc[i][j][3])) + bv;
        const long pm = (long)((m0 + wr + i * 16 + rg) >> 2);
        C[pm * N + gn] = (bf16_t)v;
      }
    }
  } else {
    __syncthreads();
    char* scr = AsB + wid * 4096;
#pragma unroll
    for (int i = 0; i < 4; i++) {
#pragma unroll
      for (int j = 0; j < 4; j++)
        *(f32x4*)(scr + l15 * 256 + ((((j * 16 + rg) << 2)) ^ ((l15 & 7) << 4))) = acc[i][j];
#pragma unroll
      for (int k = 0; k < 4; k++) {
        const int rl = k * 4 + (lane >> 4);
        const int cb = (lane & 15) << 4;
        const f32x4 v = *(const f32x4*)(scr + rl * 256 + (cb ^ ((rl & 7) << 4)));
        const long gm = m0 + wr + i * 16 + rl;
        const int gn = n0 + wc + ((lane & 15) << 2);
        const float4 bv = *(const float4*)(bias + gn);
        float vv[4] = {v[0] + bv.x, v[1] + bv.y, v[2] + bv.z, v[3] + bv.w};
        if constexpr (ACT == 1) {
#pragma unroll
          for (int r = 0; r < 4; r++) vv[r] = gelu_tanh(vv[r]);
        }
        bf16x4 o;
#pragma unroll
        for (int r = 0; r < 4; r++) o[r] = (bf16_t)vv[r];
        *(bf16x4*)(C + gm * N + gn) = o;
      }
    }
  }
}

// ===== 4-wave GEMM (dbuf, BM=64) — proj / fc2, staged coalesced epilogue =====
template <int HASRES, int OF32, int RF32>
__global__ __launch_bounds__(256) void gemm_t(
    const bf16_t* __restrict__ A, const bf16_t* __restrict__ W,
    const float* __restrict__ bias, const void* __restrict__ resv,
    void* __restrict__ Cv, int M, int N, int K) {
  constexpr int BM = 64;
  constexpr int PA = BM / 32;
  constexpr int ABYTES = BM * 128;
  constexpr int BUFSZ = ABYTES + 128 * 128;
  __shared__ __align__(16) char LDSB[2 * BUFSZ];

  const int nwg = gridDim.x;
  const int q = nwg >> 3, rm = nwg & 7;
  const int xcd = blockIdx.x & 7, idx = blockIdx.x >> 3;
  const int wg = (xcd < rm ? xcd * (q + 1) : rm * (q + 1) + (xcd - rm) * q) + idx;

  const int nbn = N >> 7;
  const int bmi = wg / nbn;
  const int bni = wg - bmi * nbn;
  const int m0 = bmi * BM, n0 = bni << 7;
  const int tid = threadIdx.x;
  const int lane = tid & 63;
  const int wid = tid >> 6;
  const int wr = (wid >> 1) * 32, wc = (wid & 1) * 64;
  const int l15 = lane & 15;
  const int lkb = (lane >> 4) << 4;
  const int srow = tid >> 3;
  const int scolsw = ((tid & 7) << 3) ^ ((srow & 7) << 3);
  const int swzr = (l15 & 7) << 4;

  f32x4 acc[PA][4];
  const f32x4 zero = {0.f, 0.f, 0.f, 0.f};
#pragma unroll
  for (int i = 0; i < PA; i++)
#pragma unroll
    for (int j = 0; j < 4; j++) acc[i][j] = zero;

  long arow[PA];
#pragma unroll
  for (int p = 0; p < PA; p++) arow[p] = m0 + srow + p * 32;
  long wrow[4];
#pragma unroll
  for (int p = 0; p < 4; p++) wrow[p] = (long)(n0 + srow + p * 32);

  auto stage = [&](int buf, int k0) {
    char* base = LDSB + buf * BUFSZ;
#pragma unroll
    for (int p = 0; p < PA; p++)
      gload_lds16(A + arow[p] * K + k0 + scolsw, (bf16_t*)(base + p * 4096 + tid * 16));
#pragma unroll
    for (int p = 0; p < 4; p++)
      gload_lds16(W + wrow[p] * K + k0 + scolsw,
                  (bf16_t*)(base + ABYTES + p * 4096 + tid * 16));
  };

  const int nt = K >> 6;
  stage(0, 0);
  int cur = 0;
  for (int t = 0; t < nt; t++) {
    __syncthreads();
    if (t + 1 < nt) stage(cur ^ 1, (t + 1) << 6);
    const char* base = LDSB + cur * BUFSZ;
#pragma unroll
    for (int kk = 0; kk < 2; kk++) {
      bf16x8 af[PA], wf[4];
#pragma unroll
      for (int i = 0; i < PA; i++)
        af[i] = *(const bf16x8*)(base + (wr + i * 16 + l15) * 128 + ((kk * 64 + lkb) ^ swzr));
#pragma unroll
      for (int j = 0; j < 4; j++)
        wf[j] = *(const bf16x8*)(base + ABYTES + (wc + j * 16 + l15) * 128 +
                                 ((kk * 64 + lkb) ^ swzr));
#pragma unroll
      for (int i = 0; i < PA; i++)
#pragma unroll
        for (int j = 0; j < 4; j++) acc[i][j] = mfma16(wf[j], af[i], acc[i][j]);
    }
    cur ^= 1;
  }

  __syncthreads();
  char* scr = LDSB + wid * 8192;
  const int rg = (lane >> 4) * 4;
#pragma unroll
  for (int i = 0; i < PA; i++) {
    const int ml = i * 16 + l15;
#pragma unroll
    for (int j = 0; j < 4; j++)
      *(f32x4*)(scr + ml * 256 + ((((j * 16 + rg) << 2)) ^ ((ml & 7) << 4))) = acc[i][j];
  }
#pragma unroll
  for (int k = 0; k < 8; k++) {
    const int rl = k * 4 + (lane >> 4);
    const int cb = (lane & 15) << 4;
    const f32x4 v = *(const f32x4*)(scr + rl * 256 + (cb ^ ((rl & 7) << 4)));
    const long gm = m0 + wr + rl;
    const int gn = n0 + wc + ((lane & 15) << 2);
    const float4 bv = *(const float4*)(bias + gn);
    float vv[4] = {v[0] + bv.x, v[1] + bv.y, v[2] + bv.z, v[3] + bv.w};
    if constexpr (HASRES) {
      if constexpr (RF32) {
        const float4 rv = *(const float4*)((const float*)resv + gm * N + gn);
        vv[0] += rv.x; vv[1] += rv.y; vv[2] += rv.z; vv[3] += rv.w;
      } else {
        const bf16x4 rv = *(const bf16x4*)((const bf16_t*)resv + gm * N + gn);
#pragma unroll
        for (int r = 0; r < 4; r++) vv[r] += (float)rv[r];
      }
    }
    if constexpr (OF32) {
      float4 o = {vv[0], vv[1], vv[2], vv[3]};
      *(float4*)((float*)Cv + gm * N + gn) = o;
    } else {
      bf16x4 o;
#pragma unroll
      for (int r = 0; r < 4; r++) o[r] = (bf16_t)vv[r];
      *(bf16x4*)((bf16_t*)Cv + gm * N + gn) = o;
    }
  }
}

// ===== FUSED qkv + attention (v1 + staged obuf write): block = (b,w), 6 waves =====
// v1 structure (full acc[4][4], compiler-pipelined W loads). PV output staged
// through Qs (P dead) -> 2 full-line bf16x8 stores. SEPARATE Qs/Kb buffers
// (r19 aliasing experiment broke numerics — keep them distinct).
__global__ __launch_bounds__(384) void qkv_attn_kernel(
    const bf16_t* __restrict__ x, const bf16_t* __restrict__ Wqkv,
    const float* __restrict__ bq, float* __restrict__ prob,
    bf16_t* __restrict__ obuf) {
  __shared__ __align__(16) char As[64 * 384];     // x-tile, 384B rows, swizzled
  __shared__ __align__(16) char Qs[6][2048];      // Qp / P / O per wave (swizzled)
  __shared__ __align__(16) char Kb[6][4096];      // K/V half-bounce per wave
  const int b = blockIdx.x / NW_;
  const int w = blockIdx.x - b * NW_;
  const int tid = threadIdx.x;
  const int lane = tid & 63;
  const int h = tid >> 6;                         // wave = head
  const int l15 = lane & 15;
  const int lk8 = (lane >> 4) * 8;
  const int lkb = (lane >> 4) << 4;
  const int rg = (lane >> 4) * 4;
  const f32x4 zero = {0.f, 0.f, 0.f, 0.f};

  // ---- stage x-tile: rows inner=0..63 (global t = inner*49 + w), swizzled src ----
#pragma unroll
  for (int i = 0; i < 4; i++) {
    const int row = i * 16 + tid / 24;
    const int cb = ((tid % 24) * 16) ^ ((row & 7) << 4);
    gload_lds16(x + ((long)b * NT_ + (long)row * NW_ + w) * DIN_ + cb / 2,
                (bf16_t*)(As + i * 6144 + tid * 16));
  }
  __syncthreads();

  char* Qw = Qs[h];
  char* Bw = Kb[h];
  auto gemm_part = [&](int which, f32x4 (&acc)[4][4]) {
#pragma unroll
    for (int i = 0; i < 4; i++)
#pragma unroll
      for (int j = 0; j < 4; j++) acc[i][j] = zero;
#pragma unroll
    for (int j = 0; j < 4; j++) {
      const bf16_t* wrow = Wqkv + (long)(which * DOUT_ + h * HD_ + j * 16 + l15) * DIN_;
      bf16x8 wf[6];
#pragma unroll
      for (int ks = 0; ks < 6; ks++)
        wf[ks] = *(const bf16x8*)(wrow + ks * 32 + lk8);
#pragma unroll
      for (int ks = 0; ks < 6; ks++) {
#pragma unroll
        for (int i = 0; i < 4; i++) {
          const int mr = i * 16 + l15;
          const bf16x8 af = *(const bf16x8*)(As + mr * 384 +
                                             ((ks * 64 + lkb) ^ ((mr & 7) << 4)));
          acc[i][j] = mfma16(af, wf[ks], acc[i][j]);
        }
      }
    }
  };

  f32x4 acc[4][4];
  // ---- q: compute, bias, pool(max over i == qs), scale, -> Qs ----
  gemm_part(0, acc);
#pragma unroll
  for (int j = 0; j < 4; j++) {
    const float bb = bq[h * HD_ + j * 16 + l15];
#pragma unroll
    for (int r = 0; r < 4; r++) {
      const float v = (fmaxf(fmaxf(acc[0][j][r], acc[1][j][r]),
                             fmaxf(acc[2][j][r], acc[3][j][r])) + bb) * 0.125f;
      const int row = rg + r;
      *(bf16_t*)(Qw + row * 128 + (((j * 16 + l15) * 2) ^ ((row & 7) << 4))) = (bf16_t)v;
    }
  }
  bf16x8 aq[2];
#pragma unroll
  for (int kc = 0; kc < 2; kc++)
    aq[kc] = *(const bf16x8*)(Qw + l15 * 128 + ((kc * 64 + lkb) ^ ((l15 & 7) << 4)));

  // ---- k: compute + bias; bounce tok-halves; S = Qp @ K^T ----
  gemm_part(1, acc);
#pragma unroll
  for (int j = 0; j < 4; j++) {
    const float bb = bq[DOUT_ + h * HD_ + j * 16 + l15];
#pragma unroll
    for (int i = 0; i < 4; i++)
#pragma unroll
      for (int r = 0; r < 4; r++) acc[i][j][r] += bb;
  }
  f32x4 s4[4];
#pragma unroll
  for (int nc = 0; nc < 4; nc++) s4[nc] = zero;
#pragma unroll
  for (int t = 0; t < 2; t++) {
#pragma unroll
    for (int i2 = 0; i2 < 2; i2++) {
      const int i = t * 2 + i2;
#pragma unroll
      for (int j = 0; j < 4; j++)
#pragma unroll
        for (int r = 0; r < 4; r++) {
          const int tokh = i2 * 16 + rg + r;
          *(bf16_t*)(Bw + tokh * 128 + (((j * 16 + l15) * 2) ^ ((tokh & 7) << 4))) =
              (bf16_t)acc[i][j][r];
        }
    }
#pragma unroll
    for (int nch = 0; nch < 2; nch++) {
      const int nc = t * 2 + nch;
      const int tokh = nch * 16 + l15;
#pragma unroll
      for (int kc = 0; kc < 2; kc++) {
        const bf16x8 bk = *(const bf16x8*)(Bw + tokh * 128 +
                                           ((kc * 64 + lkb) ^ ((tokh & 7) << 4)));
        s4[nc] = mfma16(aq[kc], bk, s4[nc]);
      }
    }
  }

  // ---- softmax (rows = rg + r) ----
#pragma unroll
  for (int r = 0; r < 4; r++) {
    float mx = fmaxf(fmaxf(s4[0][r], s4[1][r]), fmaxf(s4[2][r], s4[3][r]));
#pragma unroll
    for (int off = 1; off < 16; off <<= 1) mx = fmaxf(mx, __shfl_xor(mx, off));
    float sm = 0.f;
#pragma unroll
    for (int nc = 0; nc < 4; nc++) {
      const float p = __expf(s4[nc][r] - mx);
      s4[nc][r] = p;
      sm += p;
    }
#pragma unroll
    for (int off = 1; off < 16; off <<= 1) sm += __shfl_xor(sm, off);
    const float inv = 1.f / sm;
#pragma unroll
    for (int nc = 0; nc < 4; nc++) s4[nc][r] *= inv;
  }

  // ---- prob write (f32) + P -> Qs (reuse, swizzled) ----
  float* aout = prob + (long)((b * NH_ + h) * NW_ + w) * (WSZ_ * 64);
#pragma unroll
  for (int nc = 0; nc < 4; nc++) {
#pragma unroll
    for (int r = 0; r < 4; r++) {
      const int row = rg + r, col = nc * 16 + l15;
      aout[row * 64 + col] = s4[nc][r];
      *(bf16_t*)(Qw + row * 128 + ((col * 2) ^ ((row & 7) << 4))) = (bf16_t)s4[nc][r];
    }
  }
  bf16x8 ap[2];
#pragma unroll
  for (int kc = 0; kc < 2; kc++)
    ap[kc] = *(const bf16x8*)(Qw + l15 * 128 + ((kc * 64 + lkb) ^ ((l15 & 7) << 4)));

  // ---- v: compute + bias; bounce tok-halves; o = P @ V ----
  gemm_part(2, acc);
#pragma unroll
  for (int j = 0; j < 4; j++) {
    const float bb = bq[2 * DOUT_ + h * HD_ + j * 16 + l15];
#pragma unroll
    for (int i = 0; i < 4; i++)
#pragma unroll
      for (int r = 0; r < 4; r++) acc[i][j][r] += bb;
  }
  f32x4 o4[4];
#pragma unroll
  for (int nc = 0; nc < 4; nc++) o4[nc] = zero;
#pragma unroll
  for (int t = 0; t < 2; t++) {
#pragma unroll
    for (int i2 = 0; i2 < 2; i2++) {
      const int i = t * 2 + i2;
#pragma unroll
      for (int j = 0; j < 4; j++)
#pragma unroll
        for (int r = 0; r < 4; r++) {
          const int tokh = i2 * 16 + rg + r;
          *(bf16_t*)(Bw + tokh * 128 + (((j * 16 + l15) * 2) ^ ((tokh & 7) << 4))) =
              (bf16_t)acc[i][j][r];
        }
    }
#pragma unroll
    for (int nc = 0; nc < 4; nc++) {
      bf16x8 bv;
#pragma unroll
      for (int e = 0; e < 8; e++) {
        const int tokh = lk8 + e;
        bv[e] = *(const bf16_t*)(Bw + tokh * 128 +
                                 (((nc * 16 + l15) * 2) ^ ((tokh & 7) << 4)));
      }
      o4[nc] = mfma16(ap[t], bv, o4[nc]);
    }
  }

  // ---- staged obuf write: o -> Qs (P dead), 2 full-line bf16x8 stores ----
#pragma unroll
  for (int nc = 0; nc < 4; nc++) {
#pragma unroll
    for (int r = 0; r < 4; r++) {
      const int row = rg + r;
      *(bf16_t*)(Qw + row * 128 + (((nc * 16 + l15) * 2) ^ ((row & 7) << 4))) =
          (bf16_t)o4[nc][r];
    }
  }
  bf16_t* ob = obuf + (long)b * TP_ * DOUT_ + h * HD_;
#pragma unroll
  for (int p = 0; p < 2; p++) {
    const int row = lane >> 2;                       // ws 0..15
    const int cb = p * 64 + (lane & 3) * 16;         // byte col in [0,128)
    const bf16x8 t = *(const bf16x8*)(Qw + row * 128 + (cb ^ ((row & 7) << 4)));
    *(bf16x8*)(ob + (long)(row * NW_ + w) * DOUT_ + cb / 2) = t;
  }
}

extern "C" void kernel_launch(void* const* d_in, const int* in_sizes, int n_in,
                              void* d_out, int out_size, void* d_ws, size_t ws_size,
                              hipStream_t stream) {
  const float* emb   = (const float*)d_in[0];
  const float* n1w   = (const float*)d_in[1];
  const float* n1b   = (const float*)d_in[2];
  const float* wqkv  = (const float*)d_in[3];
  const float* bqkv  = (const float*)d_in[4];
  const float* wproj = (const float*)d_in[5];
  const float* bproj = (const float*)d_in[6];
  const float* wres  = (const float*)d_in[7];
  const float* bres  = (const float*)d_in[8];
  const float* n2w   = (const float*)d_in[9];
  const float* n2b   = (const float*)d_in[10];
  const float* wfc1  = (const float*)d_in[11];
  const float* bfc1  = (const float*)d_in[12];
  const float* wfc2  = (const float*)d_in[13];
  const float* bfc2  = (const float*)d_in[14];
  float* out = (float*)d_out;

  const int BT = NB_ * NT_;    // 100352
  const int BTP = NB_ * TP_;   // 25088

  char* wsb = (char*)d_ws;
  bf16_t* x    = (bf16_t*)(wsb);
  bf16_t* h1   = (bf16_t*)(wsb);
  bf16_t* obuf = (bf16_t*)(wsb + 57802752L);
  bf16_t* resp = (bf16_t*)(wsb + 77070336L);
  bf16_t* h0   = resp;
  bf16_t* emb1 = (bf16_t*)(wsb + 96337920L);
  bf16_t* wbqkv = (bf16_t*)(wsb + 115605504L);
  bf16_t* wbres = wbqkv + 221184L;
  bf16_t* wbproj = wbres + 73728L;
  bf16_t* wbfc1 = wbproj + 147456L;
  bf16_t* wbfc2 = wbfc1 + 589824L;
  float*  prob = out + 9633792L;   // attn-probs half of d_out

  // 0. weight cache f32 -> bf16
  cvt_kernel<<<792, 256, 0, stream>>>(wqkv, wres, wproj, wfc1, wfc2,
                                      wbqkv, wbres, wbproj, wbfc1, wbfc2);
  // 1. LN1: emb f32 -> x bf16 (ws)
  ln_f32_kernel<DIN_><<<BT / 4, 256, 0, stream>>>(emb, n1w, n1b, x);
  // 2. res projection + fused q-stride max-pool -> resp bf16
  gemm8<0, 1><<<(BT / 256) * (DOUT_ / 128), 512, 0, stream>>>(
      x, wbres, bres, resp, BT, DOUT_, DIN_);
  // 3. FUSED qkv + attention -> prob (d_out) + obuf
  qkv_attn_kernel<<<NB_ * NW_, 384, 0, stream>>>(x, wbqkv, bqkv, prob, obuf);
  // 4. attn proj + pooled residual -> emb1 bf16
  gemm_t<1, 0, 0><<<(BTP / 64) * (DOUT_ / 128), 256, 0, stream>>>(
      obuf, wbproj, bproj, resp, emb1, BTP, DOUT_, DOUT_);
  // 5. LN2: emb1 bf16 -> h0 bf16
  ln_bf16_kernel<DOUT_><<<BTP / 4, 256, 0, stream>>>(emb1, n2w, n2b, h0);
  // 6. fc1 + GELU -> h1 bf16
  gemm8<1, 0><<<(BTP / 256) * (MLP_ / 128), 512, 0, stream>>>(
      h0, wbfc1, bfc1, h1, BTP, MLP_, DOUT_);
  // 7. fc2 + emb1 residual -> d_out emb half f32
  gemm_t<1, 1, 0><<<(BTP / 64) * (DOUT_ / 128), 256, 0, stream>>>(
      h1, wbfc2, bfc2, emb1, out, BTP, DOUT_, MLP_);
}